// Round 1
// baseline (89.130 us; speedup 1.0000x reference)
//
#include <hip/hip_runtime.h>

// SparseLookupTable via one-hot MFMA:
//   out[b,o] = sum_k lut[inp[b,k], wgt[o,k]],  B=512, O=1024, K=128, LUT 256x256.
// Reformulated as out = sum_k A_k * B_k with
//   A_k[b, j] = lut[inp[b,k], j]        (dense f16 row-gather from LDS, ds_read_b128)
//   B_k[j, o] = (wgt[o,k] == j) ? 1 : 0 (one-hot, built in VALU registers)
// MFMA f32_16x16x32_f16 contracts the 256-wide one-hot dim (8 steps of K=32).
// Since B is synthesized, any hw k-permutation within a fragment cancels as long
// as A-load and B-construction use the same (lane,elem)->j convention.
//
// Block: 1024 thr (16 waves), tile 32(M) x 64(N), grid 16x16 = 256 blocks (1/CU).
// K-split 16: wave w handles kslices w*8..w*8+7; LDS-tree reduction epilogue.
// LDS: 128 KB swizzled f16 LUT + 8 KB i-idx + 16 KB w-idx = 152 KB.

#define KDIM 128

typedef _Float16 f16x8 __attribute__((ext_vector_type(8)));
typedef float    f32x4 __attribute__((ext_vector_type(4)));

union F16Frag { uint4 u; f16x8 h; };

__global__ __launch_bounds__(1024, 4)
void slt_mfma(const int* __restrict__ inp, const int* __restrict__ wgt,
              const float* __restrict__ lut, float* __restrict__ out)
{
    // 131072 (LUT f16, XOR-swizzled rows) + 8192 (i_lds [128][32] u16)
    // + 16384 (w_lds [128][64] u16) = 155648 B
    __shared__ __attribute__((aligned(16))) unsigned char smem[155648];
    unsigned char*  lutB  = smem;
    unsigned short* i_lds = (unsigned short*)(smem + 131072);
    unsigned short* w_lds = (unsigned short*)(smem + 139264);

    const int tid   = threadIdx.x;
    const int otile = blockIdx.x;   // 16 tiles of 64 outputs
    const int btile = blockIdx.y;   // 16 tiles of 32 batch rows

    // ---- stage LUT fp32 -> fp16 into LDS, row-XOR swizzle on bits 4..8 ----
    // phys(r, j) = r*512 + ((j*2) ^ ((r&31)<<4)); bijective within each 512B row,
    // preserves 8B/16B alignment (XOR touches bits >= 4 only).
    {
        const float4* lut4 = (const float4*)lut;
        #pragma unroll
        for (int it = 0; it < 16; ++it) {
            int idx = it * 1024 + tid;
            float4 v = lut4[idx];
            union { _Float16 h[4]; unsigned long long u; } pk;
            pk.h[0] = (_Float16)v.x; pk.h[1] = (_Float16)v.y;
            pk.h[2] = (_Float16)v.z; pk.h[3] = (_Float16)v.w;
            unsigned r   = (unsigned)idx >> 6;          // LUT row
            unsigned jb  = ((unsigned)idx & 63u) << 3;  // byte offset of 4-half group
            unsigned off = (r << 9) + (jb ^ ((r & 31u) << 4));
            *(unsigned long long*)(lutB + off) = pk.u;
        }
    }

    // ---- stage indices transposed, u16: i_lds[k][b], w_lds[k][o] ----
    {
        int b = tid >> 5, kg = tid & 31;
        int4 iv = *(const int4*)(inp + (size_t)(btile * 32 + b) * KDIM + kg * 4);
        i_lds[(kg*4+0)*32 + b] = (unsigned short)(iv.x & 255);
        i_lds[(kg*4+1)*32 + b] = (unsigned short)(iv.y & 255);
        i_lds[(kg*4+2)*32 + b] = (unsigned short)(iv.z & 255);
        i_lds[(kg*4+3)*32 + b] = (unsigned short)(iv.w & 255);
    }
    #pragma unroll
    for (int s2 = 0; s2 < 2; ++s2) {
        int t2 = tid + s2 * 1024;
        int o = t2 >> 5, kg = t2 & 31;
        int4 wv4 = *(const int4*)(wgt + (size_t)(otile * 64 + o) * KDIM + kg * 4);
        w_lds[(kg*4+0)*64 + o] = (unsigned short)(wv4.x & 255);
        w_lds[(kg*4+1)*64 + o] = (unsigned short)(wv4.y & 255);
        w_lds[(kg*4+2)*64 + o] = (unsigned short)(wv4.z & 255);
        w_lds[(kg*4+3)*64 + o] = (unsigned short)(wv4.w & 255);
    }
    __syncthreads();

    const int      lane = tid & 63;
    const int      wid  = tid >> 6;                       // 0..15, K-split id
    const unsigned colq = (unsigned)(lane & 15);          // A row / B col / D col
    const unsigned h8   = ((unsigned)((lane >> 4) & 3)) << 3;  // k-group * 8
    const unsigned h16  = h8 << 1;                        // byte offset of k-group

    f32x4 zero4 = {0.f, 0.f, 0.f, 0.f};
    f32x4 acc[2][4];
    #pragma unroll
    for (int a = 0; a < 2; ++a)
        #pragma unroll
        for (int b2 = 0; b2 < 4; ++b2)
            acc[a][b2] = zero4;

    // ---- main loop: 8 kslices per wave ----
    #pragma unroll 1
    for (int j = 0; j < 8; ++j) {
        const int ks = wid * 8 + j;

        // A rows for the two 16-row M-tiles (this lane's row within each tile)
        unsigned i0 = i_lds[ks * 32 + colq];
        unsigned i1 = i_lds[ks * 32 + 16 + colq];
        const unsigned rb0 = i0 << 9, sw0 = (i0 & 31u) << 4;
        const unsigned rb1 = i1 << 9, sw1 = (i1 & 31u) << 4;

        // One-hot prep per N-tile: each lane's fragment has at most one 1.0h,
        // live only at s-step sl[nt], pre-placed into p[nt][0..3].
        unsigned p[4][4]; unsigned sl[4];
        #pragma unroll
        for (int nt = 0; nt < 4; ++nt) {
            unsigned wv   = w_lds[ks * 64 + nt * 16 + colq];
            unsigned u    = wv - h8;                 // wraps huge if wv < h8 -> invalid
            unsigned slot = u & 7u;
            unsigned long long pk = 0x3C00ULL << ((slot & 3u) << 4); // f16 1.0 placed
            unsigned lo = (unsigned)pk, hi = (unsigned)(pk >> 32);
            unsigned lh    = (slot < 4u);
            unsigned valid = ((u & 31u) < 8u);
            sl[nt] = valid ? (u >> 5) : 0xFFu;       // sentinel: never matches s
            p[nt][0] = lh ? lo : 0u;
            p[nt][1] = lh ? hi : 0u;
            p[nt][2] = lh ? 0u : lo;
            p[nt][3] = lh ? 0u : hi;
        }

        // 8 MFMA K-steps of 32 over the one-hot dim
        #pragma unroll
        for (int s = 0; s < 8; ++s) {
            const unsigned su   = (unsigned)s;
            const unsigned offp = su * 64u + h16;    // byte offset within row
            F16Frag a0, a1;
            a0.u = *(const uint4*)(lutB + rb0 + (offp ^ sw0));
            a1.u = *(const uint4*)(lutB + rb1 + (offp ^ sw1));
            #pragma unroll
            for (int nt = 0; nt < 4; ++nt) {
                F16Frag bb;
                bool take = (sl[nt] == su);
                bb.u.x = take ? p[nt][0] : 0u;
                bb.u.y = take ? p[nt][1] : 0u;
                bb.u.z = take ? p[nt][2] : 0u;
                bb.u.w = take ? p[nt][3] : 0u;
                acc[0][nt] = __builtin_amdgcn_mfma_f32_16x16x32_f16(a0.h, bb.h, acc[0][nt], 0, 0, 0);
                acc[1][nt] = __builtin_amdgcn_mfma_f32_16x16x32_f16(a1.h, bb.h, acc[1][nt], 0, 0, 0);
            }
        }
    }

    // ---- cross-wave K-reduction (reuse index LDS region) + store ----
    __syncthreads();
    f32x4* red = (f32x4*)(smem + 131072);   // 1024 x f32x4 = 16 KB
    #pragma unroll
    for (int t = 0; t < 8; ++t) {
        const int mt = t >> 2, nt = t & 3;
        red[wid * 64 + ((lane >> 4) & 3) * 16 + colq] = acc[mt][nt];
        __syncthreads();
        if (tid < 64) {
            f32x4 sacc = {0.f, 0.f, 0.f, 0.f};
            #pragma unroll
            for (int w = 0; w < 16; ++w) sacc += red[w * 64 + tid];
            const int hh = tid >> 4, cc = tid & 15;
            // D layout: col = lane&15, row = (lane>>4)*4 + reg
            size_t base = (size_t)(btile * 32 + mt * 16 + hh * 4) * 1024
                        + (size_t)(otile * 64 + nt * 16 + cc);
            out[base]        = sacc[0];
            out[base + 1024] = sacc[1];
            out[base + 2048] = sacc[2];
            out[base + 3072] = sacc[3];
        }
        __syncthreads();
    }
}

extern "C" void kernel_launch(void* const* d_in, const int* in_sizes, int n_in,
                              void* d_out, int out_size, void* d_ws, size_t ws_size,
                              hipStream_t stream) {
    const int*   inp = (const int*)d_in[0];    // (512, 32, 4) int32
    const int*   wgt = (const int*)d_in[1];    // (1024, 32, 4) int32
    const float* lut = (const float*)d_in[2];  // (256, 256) fp32
    float*       out = (float*)d_out;          // (512, 1024) fp32

    dim3 grid(16, 16);
    dim3 block(1024);
    slt_mfma<<<grid, block, 0, stream>>>(inp, wgt, lut, out);
}